// Round 10
// baseline (150.007 us; speedup 1.0000x reference)
//
#include <hip/hip_runtime.h>
#include <hip/hip_bf16.h>

// Flash-attention fwd, fp32 in/out, bf16 MFMA compute.
// B=64 (batch*heads), L=1024, D=64. scale=1/sqrt(512). mask(int32)!=0 -> -1e9.
// R10 = R9 with the P C->A shuffle exchange FIXED (two perfect matchings).
//  - p_lds removed: P relayout via 8 __shfl (matchings A: src=rev2(g), B: ^1)
//  - defer-max (THR=8, log2 domain); per-lane partial l_run
//  - exp2-domain logits; mask packed to 16 bits/tile
//  - K/V double-buffered LDS, one barrier per tile; 36.9 KB -> 4 blocks/CU

typedef __attribute__((ext_vector_type(4))) float f32x4;
typedef __attribute__((ext_vector_type(8))) short bf16x8;
typedef __attribute__((ext_vector_type(4))) short short4v;

constexpr int B_ = 64;
constexpr int L_ = 1024;
constexpr int D_ = 64;
constexpr int QBLK = 64;     // q rows per block (4 waves x 16)
constexpr int KV = 64;       // keys per tile
constexpr int NKV = L_ / KV; // 16 tiles
constexpr int STR = 72;      // shorts per LDS row (64 + 8 pad)
constexpr float SC2 = 0.06376003f;   // (1/sqrt(512)) * log2(e)
constexpr float NEG = -1e9f;
constexpr float THR = 8.0f;          // defer-max threshold (log2 units, P<=256)

__device__ inline short f2bf(float f) {
  __hip_bfloat16 h = __float2bfloat16(f);
  short s; __builtin_memcpy(&s, &h, 2);
  return s;
}
__device__ inline unsigned int pk2(float a, float b) {
  return (unsigned int)(unsigned short)f2bf(a)
       | ((unsigned int)(unsigned short)f2bf(b) << 16);
}

__global__ __launch_bounds__(256, 4) void attn_fwd(
    const float* __restrict__ Q, const float* __restrict__ K,
    const float* __restrict__ V, const int* __restrict__ M,
    float* __restrict__ O)
{
  __shared__ short k_lds[2][KV][STR];   // 18.4 KB
  __shared__ short vt_lds[2][D_][STR];  // 18.4 KB  -> 36.9 KB total

  const int tid  = threadIdx.x;
  const int w    = tid >> 6;
  const int lane = tid & 63;
  const int g    = lane >> 4;
  const int c    = lane & 15;
  const int b    = blockIdx.y;
  const int q0   = blockIdx.x * QBLK;

  // ---- Q fragment (B operand of swapped QK^T): col=c -> q-row w*16+c
  bf16x8 qf[2];
  {
    const float* qp = Q + ((size_t)b * L_ + q0 + w * 16 + c) * D_ + g * 8;
#pragma unroll
    for (int ks = 0; ks < 2; ++ks) {
      f32x4 x0 = *(const f32x4*)(qp + ks * 32);
      f32x4 x1 = *(const f32x4*)(qp + ks * 32 + 4);
      bf16x8 t;
      t[0] = f2bf(x0[0]); t[1] = f2bf(x0[1]); t[2] = f2bf(x0[2]); t[3] = f2bf(x0[3]);
      t[4] = f2bf(x1[0]); t[5] = f2bf(x1[1]); t[6] = f2bf(x1[2]); t[7] = f2bf(x1[3]);
      qf[ks] = t;
    }
  }

  const float* Kb = K + (size_t)b * L_ * D_;
  const float* Vb = V + (size_t)b * L_ * D_;
  // mask, swapped layout: lane's own row q=w*16+c, keys f*16+4g+0..3 per tile
  const int* mlane = M + (size_t)b * L_ * L_ + (size_t)(q0 + w * 16 + c) * L_ + 4 * g;

  f32x4 kreg[4], vreg[4];
  const int vkey4 = (tid & 15) * 4;
  const int vd4   = (tid >> 4) * 4;

  auto load_kv = [&](int t) {
    const float* ksrc = Kb + (size_t)(t * KV) * D_;
    const float* vsrc = Vb + (size_t)(t * KV) * D_;
#pragma unroll
    for (int i = 0; i < 4; ++i) {
      kreg[i] = *(const f32x4*)(ksrc + (size_t)(tid + i * 256) * 4);
      vreg[i] = *(const f32x4*)(vsrc + (size_t)(vkey4 + i) * D_ + vd4);
    }
  };
  auto write_kv = [&](int buf) {
#pragma unroll
    for (int i = 0; i < 4; ++i) {
      const int idx = tid + i * 256;
      const int row = idx >> 4;
      const int d4  = (idx & 15) * 4;
      f32x4 kx = kreg[i];
      short4v ks4 = { f2bf(kx[0]), f2bf(kx[1]), f2bf(kx[2]), f2bf(kx[3]) };
      *(short4v*)&k_lds[buf][row][d4] = ks4;
      const int jj = (i + (tid >> 4)) & 3;   // rotated row order (bank spread)
      short4v vt4 = { f2bf(vreg[0][jj]), f2bf(vreg[1][jj]),
                      f2bf(vreg[2][jj]), f2bf(vreg[3][jj]) };
      *(short4v*)&vt_lds[buf][vd4 + jj][vkey4] = vt4;
    }
  };
  auto packm = [&](const int4* lm) {
    unsigned int mp = 0;
#pragma unroll
    for (int f = 0; f < 4; ++f) {
      mp |= (lm[f].x != 0 ? 1u : 0u) << (f * 4 + 0);
      mp |= (lm[f].y != 0 ? 1u : 0u) << (f * 4 + 1);
      mp |= (lm[f].z != 0 ? 1u : 0u) << (f * 4 + 2);
      mp |= (lm[f].w != 0 ? 1u : 0u) << (f * 4 + 3);
    }
    return mp;
  };

  f32x4 acc[4];
#pragma unroll
  for (int i = 0; i < 4; ++i) acc[i] = (f32x4){0.f, 0.f, 0.f, 0.f};
  float m_run = -INFINITY;  // row max (log2 units), row q = w*16+c
  float l_run = 0.f;        // PARTIAL sum (this lane's 16 keys/tile)

  unsigned int mcA, mcB;
  { // prologue: tile 0
    load_kv(0);
    int4 lm0[4];
#pragma unroll
    for (int f = 0; f < 4; ++f) lm0[f] = *(const int4*)(mlane + f * 16);
    write_kv(0);
    mcA = packm(lm0);
  }
  __syncthreads();

  auto body = [&](int t, bool has_next, unsigned int mc, unsigned int& mnext) {
    const int cur = t & 1;
    int4 lmn[4];
    if (has_next) {
      load_kv(t + 1);
#pragma unroll
      for (int f = 0; f < 4; ++f)
        lmn[f] = *(const int4*)(mlane + (t + 1) * KV + f * 16);
    }

    // ---- S^T = K Q^T : C row = key = f*16+g*4+r, col = q = c
    f32x4 sc[4];
#pragma unroll
    for (int f = 0; f < 4; ++f) {
      f32x4 a = (f32x4){0.f, 0.f, 0.f, 0.f};
#pragma unroll
      for (int ks = 0; ks < 2; ++ks) {
        bf16x8 kf = *(const bf16x8*)&k_lds[cur][f * 16 + c][ks * 32 + g * 8];
        a = __builtin_amdgcn_mfma_f32_16x16x32_bf16(kf, qf[ks], a, 0, 0, 0);
      }
      sc[f] = a;
    }

    // ---- mask + scale into log2 domain (bit f*4+r of mc)
#pragma unroll
    for (int f = 0; f < 4; ++f)
#pragma unroll
      for (int r = 0; r < 4; ++r)
        sc[f][r] = ((mc >> (f * 4 + r)) & 1u) ? NEG : sc[f][r] * SC2;

    // ---- online softmax, defer-max: cross-lane work only on growth tiles
    float xl = sc[0][0];
#pragma unroll
    for (int f = 0; f < 4; ++f)
#pragma unroll
      for (int r = 0; r < 4; ++r) xl = fmaxf(xl, sc[f][r]);
    if (!__all(xl <= m_run + THR)) {           // wave-uniform branch
      float x = fmaxf(xl, __shfl_xor(xl, 16, 64));
      x = fmaxf(x, __shfl_xor(x, 32, 64));
      const float m_new = fmaxf(m_run, x);
      const float alpha = exp2f(m_run - m_new);
      l_run *= alpha;
      float ar[4];
#pragma unroll
      for (int r = 0; r < 4; ++r)
        ar[r] = __shfl(alpha, (lane & 48) | (g * 4 + r), 64);
#pragma unroll
      for (int fd = 0; fd < 4; ++fd)
#pragma unroll
        for (int r = 0; r < 4; ++r) acc[fd][r] *= ar[r];
      m_run = m_new;
    }
    float s = 0.f;
#pragma unroll
    for (int f = 0; f < 4; ++f)
#pragma unroll
      for (int r = 0; r < 4; ++r) {
        const float p = exp2f(sc[f][r] - m_run);  // bounded by 2^THR = 256
        sc[f][r] = p;
        s += p;
      }
    l_run += s;

    // ---- P relayout C->A in-register: TWO perfect matchings x 4 rounds.
    // pd[f][h] = P[key=f*16+g*4+{2h,2h+1}][q=c] packed (this lane's data).
    // Matching A: target g reads source group rev2(g)={0,2,1,3}[g]; source
    // with parity p publishes pd[p+2(k>>1)][k&1]; slot d{k>>1}[(g>=2?2:0)+(k&1)].
    // Matching B: source rev2(g)^1; publishes pd[(1-p)+2(k>>1)][k&1]; slot
    // is the complementary half. Verified by spot-check on (g,c,k) cases.
    unsigned int pd[4][2];
#pragma unroll
    for (int f = 0; f < 4; ++f) {
      pd[f][0] = pk2(sc[f][0], sc[f][1]);
      pd[f][1] = pk2(sc[f][2], sc[f][3]);
    }
    const int rev2 = ((g & 1) << 1) | (g >> 1);   // 2-bit reversal of g
    const int srcA = rev2 * 16 + c;
    const int srcB = srcA ^ 16;
    const bool podd = (g & 1) != 0;
    const bool gh   = (g >= 2);
    unsigned int d0[4], d1[4];
#pragma unroll
    for (int k = 0; k < 4; ++k) {
      const int fb = 2 * (k >> 1);
      const int hh = k & 1;
      const unsigned int pubA = podd ? pd[fb + 1][hh] : pd[fb + 0][hh];
      const unsigned int pubB = podd ? pd[fb + 0][hh] : pd[fb + 1][hh];
      const unsigned int rvA = (unsigned int)__shfl((int)pubA, srcA, 64);
      const unsigned int rvB = (unsigned int)__shfl((int)pubB, srcB, 64);
      if (k < 2) {
        if (gh) { d0[2 + hh] = rvA; d0[hh] = rvB; }
        else    { d0[hh] = rvA; d0[2 + hh] = rvB; }
      } else {
        if (gh) { d1[2 + hh] = rvA; d1[hh] = rvB; }
        else    { d1[hh] = rvA; d1[2 + hh] = rvB; }
      }
    }
    bf16x8 pa0, pa1;
    __builtin_memcpy(&pa0, d0, 16);
    __builtin_memcpy(&pa1, d1, 16);

    // ---- O += P V
#pragma unroll
    for (int fd = 0; fd < 4; ++fd) {
      bf16x8 vb0 = *(const bf16x8*)&vt_lds[cur][fd * 16 + c][g * 8];
      acc[fd] = __builtin_amdgcn_mfma_f32_16x16x32_bf16(pa0, vb0, acc[fd], 0, 0, 0);
      bf16x8 vb1 = *(const bf16x8*)&vt_lds[cur][fd * 16 + c][32 + g * 8];
      acc[fd] = __builtin_amdgcn_mfma_f32_16x16x32_bf16(pa1, vb1, acc[fd], 0, 0, 0);
    }

    if (has_next) {
      write_kv(cur ^ 1);      // stage next tile into idle buffer
      mnext = packm(lmn);     // compress mask prefetch to 16 bits
    }
    __syncthreads();          // single barrier flips the buffer
  };

  for (int tt = 0; tt < NKV; tt += 2) {
    body(tt,     true,         mcA, mcB);   // tt <= 14 -> tile tt+1 exists
    body(tt + 1, tt + 2 < NKV, mcB, mcA);
  }

  // ---- epilogue: reduce partial l across the 4-lane group, normalize, store
  float l = l_run;
  l += __shfl_xor(l, 16, 64);
  l += __shfl_xor(l, 32, 64);
  const float li = 1.0f / l;
  float lr[4];
#pragma unroll
  for (int r = 0; r < 4; ++r)
    lr[r] = __shfl(li, (lane & 48) | (g * 4 + r), 64);
  float* orow = O + ((size_t)b * L_ + q0 + w * 16 + g * 4) * D_;
#pragma unroll
  for (int fd = 0; fd < 4; ++fd)
#pragma unroll
    for (int r = 0; r < 4; ++r)
      orow[(size_t)r * D_ + fd * 16 + c] = acc[fd][r] * lr[r];
}

extern "C" void kernel_launch(void* const* d_in, const int* in_sizes, int n_in,
                              void* d_out, int out_size, void* d_ws, size_t ws_size,
                              hipStream_t stream) {
  const float* q = (const float*)d_in[0];
  const float* k = (const float*)d_in[1];
  const float* v = (const float*)d_in[2];
  const int* m = (const int*)d_in[3]; // jax bool shipped as int32
  float* o = (float*)d_out;
  dim3 grid(L_ / QBLK, B_);
  attn_fwd<<<grid, 256, 0, stream>>>(q, k, v, m, o);
}